// Round 5
// baseline (397.384 us; speedup 1.0000x reference)
//
#include <hip/hip_runtime.h>
#include <math.h>

// GAT forward: B=32 N=256 F=300(pad 320) O=256 H=8 OUT=512

typedef _Float16 f16;
typedef __attribute__((ext_vector_type(8))) _Float16 f16x8;
typedef __attribute__((ext_vector_type(4))) _Float16 f16x4;
typedef __attribute__((ext_vector_type(4))) float f32x4;

__device__ __forceinline__ void async16(const void* g, void* lds) {
  __builtin_amdgcn_global_load_lds(
      (const __attribute__((address_space(1))) void*)g,
      (__attribute__((address_space(3))) void*)lds, 16, 0, 0);
}

// ---------------- prep kernels ----------------
__global__ void k_prep_x(const int* __restrict__ fea, const float* __restrict__ embed,
                         f16* __restrict__ x16) {
  int row = blockIdx.x;          // 8192
  int t = threadIdx.x;           // 320
  int tok = fea[row];
  float v = (t < 300) ? embed[tok * 300 + t] : 0.f;
  x16[(size_t)row * 320 + t] = (f16)v;
}

// W[h][t<300][o<256] -> WcT[(h*256+o)*320 + t], LDS 32x32 transpose
__global__ void k_prep_wc(const float* __restrict__ W, f16* __restrict__ WcT) {
  __shared__ float tile[32][33];
  int bx = blockIdx.x, by = blockIdx.y, h = blockIdx.z;   // (10, 8, 8)
  int tid = threadIdx.x;
  int c = tid & 31, q = tid >> 5;
#pragma unroll
  for (int i = 0; i < 4; ++i) {
    int tt = q + i * 8;
    int t = bx * 32 + tt;
    float v = (t < 300) ? W[((size_t)h * 300 + t) * 256 + by * 32 + c] : 0.f;
    tile[tt][c] = v;
  }
  __syncthreads();
#pragma unroll
  for (int i = 0; i < 4; ++i) {
    int oo = q + i * 8;
    int gc = h * 256 + by * 32 + oo;
    WcT[(size_t)gc * 320 + bx * 32 + c] = (f16)tile[c][oo];
  }
}

// W[k<2048][o2<512] -> WoT[o2*2048 + k]
__global__ void k_prep_wo(const float* __restrict__ W, f16* __restrict__ WoT) {
  __shared__ float tile[32][33];
  int bx = blockIdx.x, by = blockIdx.y;    // (64, 16)
  int tid = threadIdx.x;
  int c = tid & 31, q = tid >> 5;
#pragma unroll
  for (int i = 0; i < 4; ++i) {
    int kk = q + i * 8;
    tile[kk][c] = W[((size_t)bx * 32 + kk) * 512 + by * 32 + c];
  }
  __syncthreads();
#pragma unroll
  for (int i = 0; i < 4; ++i) {
    int oo = q + i * 8;
    WoT[((size_t)by * 32 + oo) * 2048 + bx * 32 + c] = (f16)tile[c][oo];
  }
}

// ---------------- GEMM 1 + fused e-dots (layer 1) ----------------
// outT[b][col][n] = (A @ BT^T)^T, tile 128x128, BK=32, XOR-swizzled LDS.
// LDS[row][c] = Global[row][c ^ ((row>>1)&3)]  (16B chunks) -> conflict-free b128 reads.
template <int KDIM, int NCOLS>
__global__ __launch_bounds__(256, 4) void k_gemm1(const f16* __restrict__ A,
                                                  const f16* __restrict__ BT,
                                                  f16* __restrict__ outT,
                                                  const float* __restrict__ avec,
                                                  float* __restrict__ e1,
                                                  float* __restrict__ e2) {
  __shared__ f16 As[128 * 32];
  __shared__ f16 Bs[128 * 32];
  const int by = blockIdx.x, bx = blockIdx.y;   // A-row-tile fastest (XCD locality)
  const int tid = threadIdx.x;
  const int wave = tid >> 6, lane = tid & 63;
  const int wm = wave >> 1, wn = wave & 1;
  const int lrow = lane & 15, quad = lane >> 4;
  const int srow = lane >> 2;                         // staging row within 16
  const int scol = ((lane & 3) ^ ((lane >> 3) & 3)) * 8;   // swizzled global chunk
  const int sq = (quad ^ ((lrow >> 1) & 3)) * 8;           // swizzled read chunk

  f32x4 acc[4][4] = {};
  const f16* Ag = A + (size_t)by * 128 * KDIM;
  const f16* Bg = BT + (size_t)bx * 128 * KDIM;

  for (int k0 = 0; k0 < KDIM; k0 += 32) {
    __syncthreads();
#pragma unroll
    for (int j = 0; j < 2; ++j) {
      const int r0 = wave * 32 + j * 16;
      async16(Ag + (size_t)(r0 + srow) * KDIM + k0 + scol, &As[r0 * 32]);
      async16(Bg + (size_t)(r0 + srow) * KDIM + k0 + scol, &Bs[r0 * 32]);
    }
    __syncthreads();
    f16x8 af[4], bf[4];
#pragma unroll
    for (int t = 0; t < 4; ++t) {
      af[t] = *(const f16x8*)&As[(wm * 64 + t * 16 + lrow) * 32 + sq];
      bf[t] = *(const f16x8*)&Bs[(wn * 64 + t * 16 + lrow) * 32 + sq];
    }
#pragma unroll
    for (int mt = 0; mt < 4; ++mt)
#pragma unroll
      for (int nt = 0; nt < 4; ++nt)
        acc[mt][nt] = __builtin_amdgcn_mfma_f32_16x16x32_f16(af[mt], bf[nt], acc[mt][nt], 0, 0, 0);
  }

  const int b = (by * 128) >> 8;
  const int nbase0 = (by * 128) & 255;
#pragma unroll
  for (int mt = 0; mt < 4; ++mt) {
    const int nb = nbase0 + wm * 64 + mt * 16 + quad * 4;
#pragma unroll
    for (int nt = 0; nt < 4; ++nt) {
      const int gc = bx * 128 + wn * 64 + nt * 16 + lrow;
      f16x4 v;
#pragma unroll
      for (int r = 0; r < 4; ++r) v[r] = (f16)acc[mt][nt][r];
      *(f16x4*)&outT[((size_t)b * NCOLS + gc) * 256 + nb] = v;
    }
  }

  // fused e-dot vs a_heads (block spans one head: 128 cols within h)
  float a1v[4], a2v[4];
#pragma unroll
  for (int nt = 0; nt < 4; ++nt) {
    const int gc = bx * 128 + wn * 64 + nt * 16 + lrow;
    int hh = gc >> 8, oo = gc & 255;
    a1v[nt] = avec[hh * 512 + oo];
    a2v[nt] = avec[hh * 512 + 256 + oo];
  }
  const int hblk = (bx * 128) >> 8;
  const int ebase = (b * 8 + hblk) * 256;
#pragma unroll
  for (int mt = 0; mt < 4; ++mt) {
    float s1[4] = {0.f, 0.f, 0.f, 0.f}, s2[4] = {0.f, 0.f, 0.f, 0.f};
#pragma unroll
    for (int nt = 0; nt < 4; ++nt)
#pragma unroll
      for (int r = 0; r < 4; ++r) {
        s1[r] += acc[mt][nt][r] * a1v[nt];
        s2[r] += acc[mt][nt][r] * a2v[nt];
      }
#pragma unroll
    for (int r = 0; r < 4; ++r)
#pragma unroll
      for (int m = 1; m < 16; m <<= 1) {
        s1[r] += __shfl_xor(s1[r], m);
        s2[r] += __shfl_xor(s2[r], m);
      }
    if (lrow == 0) {
      const int nb = nbase0 + wm * 64 + mt * 16 + quad * 4;
#pragma unroll
      for (int r = 0; r < 4; ++r) {
        atomicAdd(&e1[ebase + nb + r], s1[r]);
        atomicAdd(&e2[ebase + nb + r], s2[r]);
      }
    }
  }
}

// ---------------- GEMM 2: split-K x4, fp32 atomic accumulate ----------------
// M=8192, N=512, K=2048; tile 128x128, K-chunk 512; grid (64, 4, 4) = 1024 blocks.
__global__ __launch_bounds__(256, 4) void k_gemm_sk(const f16* __restrict__ A,
                                                    const f16* __restrict__ BT,
                                                    float* __restrict__ acc32) {
  __shared__ f16 As[128 * 32];
  __shared__ f16 Bs[128 * 32];
  const int by = blockIdx.x, bx = blockIdx.y, kz = blockIdx.z;
  const int tid = threadIdx.x;
  const int wave = tid >> 6, lane = tid & 63;
  const int wm = wave >> 1, wn = wave & 1;
  const int lrow = lane & 15, quad = lane >> 4;
  const int srow = lane >> 2;
  const int scol = ((lane & 3) ^ ((lane >> 3) & 3)) * 8;
  const int sq = (quad ^ ((lrow >> 1) & 3)) * 8;

  f32x4 acc[4][4] = {};
  const f16* Ag = A + (size_t)by * 128 * 2048;
  const f16* Bg = BT + (size_t)bx * 128 * 2048;
  const int kbeg = kz * 512;

  for (int k0 = kbeg; k0 < kbeg + 512; k0 += 32) {
    __syncthreads();
#pragma unroll
    for (int j = 0; j < 2; ++j) {
      const int r0 = wave * 32 + j * 16;
      async16(Ag + (size_t)(r0 + srow) * 2048 + k0 + scol, &As[r0 * 32]);
      async16(Bg + (size_t)(r0 + srow) * 2048 + k0 + scol, &Bs[r0 * 32]);
    }
    __syncthreads();
    f16x8 af[4], bf[4];
#pragma unroll
    for (int t = 0; t < 4; ++t) {
      af[t] = *(const f16x8*)&As[(wm * 64 + t * 16 + lrow) * 32 + sq];
      bf[t] = *(const f16x8*)&Bs[(wn * 64 + t * 16 + lrow) * 32 + sq];
    }
#pragma unroll
    for (int mt = 0; mt < 4; ++mt)
#pragma unroll
      for (int nt = 0; nt < 4; ++nt)
        acc[mt][nt] = __builtin_amdgcn_mfma_f32_16x16x32_f16(af[mt], bf[nt], acc[mt][nt], 0, 0, 0);
  }

  const int b = (by * 128) >> 8;
  const int nbase0 = (by * 128) & 255;
#pragma unroll
  for (int mt = 0; mt < 4; ++mt) {
    const int nb = nbase0 + wm * 64 + mt * 16 + quad * 4;
#pragma unroll
    for (int nt = 0; nt < 4; ++nt) {
      const int gc = bx * 128 + wn * 64 + nt * 16 + lrow;
      float* dst = &acc32[((size_t)b * 512 + gc) * 256 + nb];
#pragma unroll
      for (int r = 0; r < 4; ++r) atomicAdd(dst + r, acc[mt][nt][r]);
    }
  }
}

// ---------------- combine: fp32 acc -> f16 Wh2T, fused e12/e22 dots ----------------
__global__ void k_comb(const float* __restrict__ acc32, const float* __restrict__ ao,
                       f16* __restrict__ Wh2T, float* __restrict__ e12,
                       float* __restrict__ e22) {
  int oc = blockIdx.x;           // 8 chunks of 64 o2
  int b = blockIdx.y;            // 32
  int n = threadIdx.x;           // 256
  const float* base = acc32 + ((size_t)b * 512 + oc * 64) * 256 + n;
  f16* wbase = Wh2T + ((size_t)b * 512 + oc * 64) * 256 + n;
  float s1 = 0.f, s2 = 0.f;
#pragma unroll 8
  for (int j = 0; j < 64; ++j) {
    float v = base[(size_t)j * 256];
    int o2 = oc * 64 + j;
    s1 += v * ao[o2];
    s2 += v * ao[512 + o2];
    wbase[(size_t)j * 256] = (f16)v;
  }
  atomicAdd(&e12[b * 256 + n], s1);
  atomicAdd(&e22[b * 256 + n], s2);
}

#define PSTRIDE 264

// ---------------- fused attention layer 1 ----------------
// grid (h=8, b=32, nt=4)
__global__ __launch_bounds__(256, 4) void k_attn1(
    const f16* __restrict__ WhT, const float* __restrict__ e1g, const float* __restrict__ e2g,
    const int* __restrict__ adj, const float* __restrict__ npm, f16* __restrict__ h1) {
  int h = blockIdx.x, b = blockIdx.y, nt0 = blockIdx.z;
  int bh = b * 8 + h;
  int n0 = nt0 * 64;
  __shared__ f16 P[64 * PSTRIDE];
  int tid = threadIdx.x;
  int wave = tid >> 6, lane = tid & 63;

  float4 e2v = *(const float4*)&e2g[bh * 256 + lane * 4];
  float e2m = fmaxf(fmaxf(e2v.x, e2v.y), fmaxf(e2v.z, e2v.w));
#pragma unroll
  for (int m = 1; m < 64; m <<= 1) e2m = fmaxf(e2m, __shfl_xor(e2m, m));
#pragma unroll 4
  for (int i = 0; i < 16; ++i) {
    int row = i * 4 + wave;
    int gn = b * 256 + n0 + row;
    float er = e1g[bh * 256 + n0 + row];
    float sh = er + e2m;
    sh = sh > 0.f ? sh : 0.2f * sh;     // upper bound of row max
    int4 aj = *(const int4*)&adj[(size_t)gn * 256 + lane * 4];
    float p0, p1, p2, p3;
    {
      float v = er + e2v.x; v = v > 0.f ? v : 0.2f * v;
      p0 = aj.x ? __expf(v - sh) : 0.f;
      v = er + e2v.y; v = v > 0.f ? v : 0.2f * v;
      p1 = aj.y ? __expf(v - sh) : 0.f;
      v = er + e2v.z; v = v > 0.f ? v : 0.2f * v;
      p2 = aj.z ? __expf(v - sh) : 0.f;
      v = er + e2v.w; v = v > 0.f ? v : 0.2f * v;
      p3 = aj.w ? __expf(v - sh) : 0.f;
    }
    float sm = p0 + p1 + p2 + p3;
#pragma unroll
    for (int m = 1; m < 64; m <<= 1) sm += __shfl_xor(sm, m);
    float rs = 1.f / sm;
    f16x4 pw;
    pw[0] = (f16)(p0 * rs); pw[1] = (f16)(p1 * rs);
    pw[2] = (f16)(p2 * rs); pw[3] = (f16)(p3 * rs);
    *(f16x4*)&P[row * PSTRIDE + lane * 4] = pw;
  }
  __syncthreads();

  int lrow = lane & 15, quad = lane >> 4;
  f32x4 acc[4][4] = {};
  const f16* Ag = WhT + (size_t)bh * 65536;
#pragma unroll 2
  for (int k0 = 0; k0 < 256; k0 += 32) {
    f16x8 af[4], bf[4];
#pragma unroll
    for (int mt = 0; mt < 4; ++mt)
      af[mt] = *(const f16x8*)&Ag[(size_t)(wave * 64 + mt * 16 + lrow) * 256 + k0 + quad * 8];
#pragma unroll
    for (int nt = 0; nt < 4; ++nt)
      bf[nt] = *(const f16x8*)&P[(nt * 16 + lrow) * PSTRIDE + k0 + quad * 8];
#pragma unroll
    for (int mt = 0; mt < 4; ++mt)
#pragma unroll
      for (int nt = 0; nt < 4; ++nt)
        acc[mt][nt] = __builtin_amdgcn_mfma_f32_16x16x32_f16(af[mt], bf[nt], acc[mt][nt], 0, 0, 0);
  }
#pragma unroll
  for (int nt = 0; nt < 4; ++nt) {
    int nloc = nt * 16 + lrow;
    int gn = b * 256 + n0 + nloc;
    float pm = npm[gn];
#pragma unroll
    for (int mt = 0; mt < 4; ++mt) {
      int o0 = wave * 64 + mt * 16 + quad * 4;
      f16x4 st;
#pragma unroll
      for (int r = 0; r < 4; ++r) {
        float v = acc[mt][nt][r];
        v = v > 0.f ? v : (__expf(v) - 1.f);
        st[r] = (f16)(v * pm);
      }
      *(f16x4*)&h1[(size_t)gn * 2048 + h * 256 + o0] = st;
    }
  }
}

// ---------------- fused attention layer 2 ----------------
// grid (oh=2, b=32, nt=4)
__global__ __launch_bounds__(256, 4) void k_attn2(
    const f16* __restrict__ Wh2T, const float* __restrict__ e1g, const float* __restrict__ e2g,
    const int* __restrict__ adj, const float* __restrict__ npm, float* __restrict__ out) {
  int oh = blockIdx.x, b = blockIdx.y, nt0 = blockIdx.z;
  int n0 = nt0 * 64;
  __shared__ f16 P[64 * PSTRIDE];
  int tid = threadIdx.x;
  int wave = tid >> 6, lane = tid & 63;

  float4 e2v = *(const float4*)&e2g[b * 256 + lane * 4];
  float e2m = fmaxf(fmaxf(e2v.x, e2v.y), fmaxf(e2v.z, e2v.w));
#pragma unroll
  for (int m = 1; m < 64; m <<= 1) e2m = fmaxf(e2m, __shfl_xor(e2m, m));
#pragma unroll 4
  for (int i = 0; i < 16; ++i) {
    int row = i * 4 + wave;
    int gn = b * 256 + n0 + row;
    float er = e1g[b * 256 + n0 + row];
    float sh = er + e2m;
    sh = sh > 0.f ? sh : 0.2f * sh;
    int4 aj = *(const int4*)&adj[(size_t)gn * 256 + lane * 4];
    float p0, p1, p2, p3;
    {
      float v = er + e2v.x; v = v > 0.f ? v : 0.2f * v;
      p0 = aj.x ? __expf(v - sh) : 0.f;
      v = er + e2v.y; v = v > 0.f ? v : 0.2f * v;
      p1 = aj.y ? __expf(v - sh) : 0.f;
      v = er + e2v.z; v = v > 0.f ? v : 0.2f * v;
      p2 = aj.z ? __expf(v - sh) : 0.f;
      v = er + e2v.w; v = v > 0.f ? v : 0.2f * v;
      p3 = aj.w ? __expf(v - sh) : 0.f;
    }
    float sm = p0 + p1 + p2 + p3;
#pragma unroll
    for (int m = 1; m < 64; m <<= 1) sm += __shfl_xor(sm, m);
    float rs = 1.f / sm;
    f16x4 pw;
    pw[0] = (f16)(p0 * rs); pw[1] = (f16)(p1 * rs);
    pw[2] = (f16)(p2 * rs); pw[3] = (f16)(p3 * rs);
    *(f16x4*)&P[row * PSTRIDE + lane * 4] = pw;
  }
  __syncthreads();

  int lrow = lane & 15, quad = lane >> 4;
  f32x4 acc[4][4] = {};
  const f16* Ag = Wh2T + (size_t)b * 512 * 256 + (size_t)oh * 65536;
#pragma unroll 2
  for (int k0 = 0; k0 < 256; k0 += 32) {
    f16x8 af[4], bf[4];
#pragma unroll
    for (int mt = 0; mt < 4; ++mt)
      af[mt] = *(const f16x8*)&Ag[(size_t)(wave * 64 + mt * 16 + lrow) * 256 + k0 + quad * 8];
#pragma unroll
    for (int nt = 0; nt < 4; ++nt)
      bf[nt] = *(const f16x8*)&P[(nt * 16 + lrow) * PSTRIDE + k0 + quad * 8];
#pragma unroll
    for (int mt = 0; mt < 4; ++mt)
#pragma unroll
      for (int nt = 0; nt < 4; ++nt)
        acc[mt][nt] = __builtin_amdgcn_mfma_f32_16x16x32_f16(af[mt], bf[nt], acc[mt][nt], 0, 0, 0);
  }
#pragma unroll
  for (int nt = 0; nt < 4; ++nt) {
    int nloc = nt * 16 + lrow;
    int gn = b * 256 + n0 + nloc;
    float pm = npm[gn];
#pragma unroll
    for (int mt = 0; mt < 4; ++mt) {
      int o0 = oh * 256 + wave * 64 + mt * 16 + quad * 4;
      float4 st;
      float v0 = acc[mt][nt][0] * pm;
      float v1 = acc[mt][nt][1] * pm;
      float v2 = acc[mt][nt][2] * pm;
      float v3 = acc[mt][nt][3] * pm;
      st.x = v0 > 0.f ? v0 : (__expf(v0) - 1.f);
      st.y = v1 > 0.f ? v1 : (__expf(v1) - 1.f);
      st.z = v2 > 0.f ? v2 : (__expf(v2) - 1.f);
      st.w = v3 > 0.f ? v3 : (__expf(v3) - 1.f);
      *(float4*)&out[(size_t)gn * 512 + o0] = st;
    }
  }
}

extern "C" void kernel_launch(void* const* d_in, const int* in_sizes, int n_in,
                              void* d_out, int out_size, void* d_ws, size_t ws_size,
                              hipStream_t stream) {
  (void)in_sizes; (void)n_in; (void)out_size; (void)ws_size;
  const int*   fea   = (const int*)d_in[0];
  const int*   adj   = (const int*)d_in[1];
  const float* npm   = (const float*)d_in[2];
  const float* embed = (const float*)d_in[3];
  const float* Whd   = (const float*)d_in[4];
  const float* ah    = (const float*)d_in[5];
  const float* Wo    = (const float*)d_in[6];
  const float* ao    = (const float*)d_in[7];
  float* out = (float*)d_out;

  char* ws = (char*)d_ws;
  f16* x16  = (f16*)ws;  ws += (size_t)8192 * 320 * 2;
  f16* WcT  = (f16*)ws;  ws += (size_t)2048 * 320 * 2;
  f16* WoT  = (f16*)ws;  ws += (size_t)512 * 2048 * 2;
  f16* WhT  = (f16*)ws;  ws += (size_t)32 * 8 * 256 * 256 * 2;   // [b][h*256+o][n]
  f16* h1   = (f16*)ws;  ws += (size_t)8192 * 2048 * 2;          // [bn][h*256+o]
  f16* Wh2T = (f16*)ws;  ws += (size_t)32 * 512 * 256 * 2;       // [b][o2][n]
  // contiguous zero-init region: Wh2acc + all e-accumulators
  float* Wh2acc = (float*)ws; ws += (size_t)32 * 512 * 256 * 4;  // fp32 split-K acc
  float* e1  = (float*)ws; ws += (size_t)65536 * 4;
  float* e2  = (float*)ws; ws += (size_t)65536 * 4;
  float* e12 = (float*)ws; ws += (size_t)8192 * 4;
  float* e22 = (float*)ws; ws += (size_t)8192 * 4;

  hipMemsetAsync(Wh2acc, 0,
                 ((size_t)32 * 512 * 256 + 65536 * 2 + 8192 * 2) * 4, stream);

  k_prep_x<<<8192, 320, 0, stream>>>(fea, embed, x16);
  k_prep_wc<<<dim3(10, 8, 8), 256, 0, stream>>>(Whd, WcT);
  k_prep_wo<<<dim3(64, 16), 256, 0, stream>>>(Wo, WoT);

  k_gemm1<320, 2048><<<dim3(64, 16), 256, 0, stream>>>(x16, WcT, WhT, ah, e1, e2);
  k_attn1<<<dim3(8, 32, 4), 256, 0, stream>>>(WhT, e1, e2, adj, npm, h1);

  k_gemm_sk<<<dim3(64, 4, 4), 256, 0, stream>>>(h1, WoT, Wh2acc);
  k_comb<<<dim3(8, 32), 256, 0, stream>>>(Wh2acc, ao, Wh2T, e12, e22);
  k_attn2<<<dim3(2, 32, 4), 256, 0, stream>>>(Wh2T, e12, e22, adj, npm, out);
}

// Round 6
// 207.494 us; speedup vs baseline: 1.9152x; 1.9152x over previous
//
#include <hip/hip_runtime.h>
#include <math.h>

// GAT forward: B=32 N=256 F=300(pad 320) O=256 H=8 OUT=512

typedef _Float16 f16;
typedef __attribute__((ext_vector_type(8))) _Float16 f16x8;
typedef __attribute__((ext_vector_type(4))) _Float16 f16x4;
typedef __attribute__((ext_vector_type(4))) float f32x4;

__device__ __forceinline__ void async16(const void* g, void* lds) {
  __builtin_amdgcn_global_load_lds(
      (const __attribute__((address_space(1))) void*)g,
      (__attribute__((address_space(3))) void*)lds, 16, 0, 0);
}

// ---------------- prep kernels ----------------
__global__ void k_prep_x(const int* __restrict__ fea, const float* __restrict__ embed,
                         f16* __restrict__ x16) {
  int row = blockIdx.x;          // 8192
  int t = threadIdx.x;           // 320
  int tok = fea[row];
  float v = (t < 300) ? embed[tok * 300 + t] : 0.f;
  x16[(size_t)row * 320 + t] = (f16)v;
}

// W[h][t<300][o<256] -> WcT[(h*256+o)*320 + t], LDS 32x32 transpose
__global__ void k_prep_wc(const float* __restrict__ W, f16* __restrict__ WcT) {
  __shared__ float tile[32][33];
  int bx = blockIdx.x, by = blockIdx.y, h = blockIdx.z;   // (10, 8, 8)
  int tid = threadIdx.x;
  int c = tid & 31, q = tid >> 5;
#pragma unroll
  for (int i = 0; i < 4; ++i) {
    int tt = q + i * 8;
    int t = bx * 32 + tt;
    float v = (t < 300) ? W[((size_t)h * 300 + t) * 256 + by * 32 + c] : 0.f;
    tile[tt][c] = v;
  }
  __syncthreads();
#pragma unroll
  for (int i = 0; i < 4; ++i) {
    int oo = q + i * 8;
    int gc = h * 256 + by * 32 + oo;
    WcT[(size_t)gc * 320 + bx * 32 + c] = (f16)tile[c][oo];
  }
}

// W[k<2048][o2<512] -> WoT[o2*2048 + k]
__global__ void k_prep_wo(const float* __restrict__ W, f16* __restrict__ WoT) {
  __shared__ float tile[32][33];
  int bx = blockIdx.x, by = blockIdx.y;    // (64, 16)
  int tid = threadIdx.x;
  int c = tid & 31, q = tid >> 5;
#pragma unroll
  for (int i = 0; i < 4; ++i) {
    int kk = q + i * 8;
    tile[kk][c] = W[((size_t)bx * 32 + kk) * 512 + by * 32 + c];
  }
  __syncthreads();
#pragma unroll
  for (int i = 0; i < 4; ++i) {
    int oo = q + i * 8;
    WoT[((size_t)by * 32 + oo) * 2048 + bx * 32 + c] = (f16)tile[c][oo];
  }
}

// ---------------- GEMM 1 + fused e-dots (layer 1) ----------------
// outT[b][col][n] = (A @ BT^T)^T, tile 128x128, BK=32, XOR-swizzled LDS
// (LDS[row][c] = G[row][c ^ ((row>>1)&3)], 16B chunks -> conflict-free b128, verified R5).
template <int KDIM, int NCOLS>
__global__ __launch_bounds__(256, 4) void k_gemm1(const f16* __restrict__ A,
                                                  const f16* __restrict__ BT,
                                                  f16* __restrict__ outT,
                                                  const float* __restrict__ avec,
                                                  float* __restrict__ e1,
                                                  float* __restrict__ e2) {
  __shared__ f16 As[128 * 32];
  __shared__ f16 Bs[128 * 32];
  const int by = blockIdx.x, bx = blockIdx.y;   // A-row-tile fastest (XCD locality)
  const int tid = threadIdx.x;
  const int wave = tid >> 6, lane = tid & 63;
  const int wm = wave >> 1, wn = wave & 1;
  const int lrow = lane & 15, quad = lane >> 4;
  const int srow = lane >> 2;                         // staging row within 16
  const int scol = ((lane & 3) ^ ((lane >> 3) & 3)) * 8;   // swizzled global chunk
  const int sq = (quad ^ ((lrow >> 1) & 3)) * 8;           // swizzled read chunk

  f32x4 acc[4][4] = {};
  const f16* Ag = A + (size_t)by * 128 * KDIM;
  const f16* Bg = BT + (size_t)bx * 128 * KDIM;

  for (int k0 = 0; k0 < KDIM; k0 += 32) {
    __syncthreads();
#pragma unroll
    for (int j = 0; j < 2; ++j) {
      const int r0 = wave * 32 + j * 16;
      async16(Ag + (size_t)(r0 + srow) * KDIM + k0 + scol, &As[r0 * 32]);
      async16(Bg + (size_t)(r0 + srow) * KDIM + k0 + scol, &Bs[r0 * 32]);
    }
    __syncthreads();
    f16x8 af[4], bf[4];
#pragma unroll
    for (int t = 0; t < 4; ++t) {
      af[t] = *(const f16x8*)&As[(wm * 64 + t * 16 + lrow) * 32 + sq];
      bf[t] = *(const f16x8*)&Bs[(wn * 64 + t * 16 + lrow) * 32 + sq];
    }
#pragma unroll
    for (int mt = 0; mt < 4; ++mt)
#pragma unroll
      for (int nt = 0; nt < 4; ++nt)
        acc[mt][nt] = __builtin_amdgcn_mfma_f32_16x16x32_f16(af[mt], bf[nt], acc[mt][nt], 0, 0, 0);
  }

  const int b = (by * 128) >> 8;
  const int nbase0 = (by * 128) & 255;
#pragma unroll
  for (int mt = 0; mt < 4; ++mt) {
    const int nb = nbase0 + wm * 64 + mt * 16 + quad * 4;
#pragma unroll
    for (int nt = 0; nt < 4; ++nt) {
      const int gc = bx * 128 + wn * 64 + nt * 16 + lrow;
      f16x4 v;
#pragma unroll
      for (int r = 0; r < 4; ++r) v[r] = (f16)acc[mt][nt][r];
      *(f16x4*)&outT[((size_t)b * NCOLS + gc) * 256 + nb] = v;
    }
  }

  // fused e-dot vs a_heads (block spans one head: 128 cols within h)
  float a1v[4], a2v[4];
#pragma unroll
  for (int nt = 0; nt < 4; ++nt) {
    const int gc = bx * 128 + wn * 64 + nt * 16 + lrow;
    int hh = gc >> 8, oo = gc & 255;
    a1v[nt] = avec[hh * 512 + oo];
    a2v[nt] = avec[hh * 512 + 256 + oo];
  }
  const int hblk = (bx * 128) >> 8;
  const int ebase = (b * 8 + hblk) * 256;
#pragma unroll
  for (int mt = 0; mt < 4; ++mt) {
    float s1[4] = {0.f, 0.f, 0.f, 0.f}, s2[4] = {0.f, 0.f, 0.f, 0.f};
#pragma unroll
    for (int nt = 0; nt < 4; ++nt)
#pragma unroll
      for (int r = 0; r < 4; ++r) {
        s1[r] += acc[mt][nt][r] * a1v[nt];
        s2[r] += acc[mt][nt][r] * a2v[nt];
      }
#pragma unroll
    for (int r = 0; r < 4; ++r)
#pragma unroll
      for (int m = 1; m < 16; m <<= 1) {
        s1[r] += __shfl_xor(s1[r], m);
        s2[r] += __shfl_xor(s2[r], m);
      }
    if (lrow == 0) {
      const int nb = nbase0 + wm * 64 + mt * 16 + quad * 4;
#pragma unroll
      for (int r = 0; r < 4; ++r) {
        atomicAdd(&e1[ebase + nb + r], s1[r]);
        atomicAdd(&e2[ebase + nb + r], s2[r]);
      }
    }
  }
}

// ---------------- GEMM 2: split-K x2 into DISJOINT f16 buffers (no atomics) ----------------
// M=8192, N=512, K=2048; tile 128x64, K-chunk 1024; grid (64, 8, 2) = 1024 blocks = 4/CU.
__global__ __launch_bounds__(256, 4) void k_gemm_sk(const f16* __restrict__ A,
                                                    const f16* __restrict__ BT,
                                                    f16* __restrict__ outSK) {
  __shared__ f16 As[128 * 32];
  __shared__ f16 Bs[64 * 32];
  const int by = blockIdx.x, bx = blockIdx.y, kz = blockIdx.z;
  const int tid = threadIdx.x;
  const int wave = tid >> 6, lane = tid & 63;
  const int wm = wave >> 1, wn = wave & 1;
  const int lrow = lane & 15, quad = lane >> 4;
  const int srow = lane >> 2;
  const int scol = ((lane & 3) ^ ((lane >> 3) & 3)) * 8;
  const int sq = (quad ^ ((lrow >> 1) & 3)) * 8;

  f32x4 acc[4][2] = {};
  const f16* Ag = A + (size_t)by * 128 * 2048;
  const f16* Bg = BT + (size_t)bx * 64 * 2048;
  const int kbeg = kz * 1024;

  for (int k0 = kbeg; k0 < kbeg + 1024; k0 += 32) {
    __syncthreads();
#pragma unroll
    for (int j = 0; j < 2; ++j) {
      const int r0 = wave * 32 + j * 16;
      async16(Ag + (size_t)(r0 + srow) * 2048 + k0 + scol, &As[r0 * 32]);
    }
    {
      const int r0 = wave * 16;
      async16(Bg + (size_t)(r0 + srow) * 2048 + k0 + scol, &Bs[r0 * 32]);
    }
    __syncthreads();
    f16x8 af[4], bf[2];
#pragma unroll
    for (int t = 0; t < 4; ++t)
      af[t] = *(const f16x8*)&As[(wm * 64 + t * 16 + lrow) * 32 + sq];
#pragma unroll
    for (int t = 0; t < 2; ++t)
      bf[t] = *(const f16x8*)&Bs[(wn * 32 + t * 16 + lrow) * 32 + sq];
#pragma unroll
    for (int mt = 0; mt < 4; ++mt)
#pragma unroll
      for (int nt = 0; nt < 2; ++nt)
        acc[mt][nt] = __builtin_amdgcn_mfma_f32_16x16x32_f16(af[mt], bf[nt], acc[mt][nt], 0, 0, 0);
  }

  const int b = (by * 128) >> 8;
  const int nbase0 = (by * 128) & 255;
  f16* dst = outSK + (size_t)kz * 32 * 512 * 256;
#pragma unroll
  for (int mt = 0; mt < 4; ++mt) {
    const int nb = nbase0 + wm * 64 + mt * 16 + quad * 4;
#pragma unroll
    for (int nt = 0; nt < 2; ++nt) {
      const int gc = bx * 64 + wn * 32 + nt * 16 + lrow;
      f16x4 v;
#pragma unroll
      for (int r = 0; r < 4; ++r) v[r] = (f16)acc[mt][nt][r];
      *(f16x4*)&dst[((size_t)b * 512 + gc) * 256 + nb] = v;
    }
  }
}

// ---------------- combine: sum 2 split-K halves -> f16 Wh2T, fused e12/e22 dots ----------------
__global__ void k_comb(const f16* __restrict__ sk, const float* __restrict__ ao,
                       f16* __restrict__ Wh2T, float* __restrict__ e12,
                       float* __restrict__ e22) {
  int oc = blockIdx.x;           // 8 chunks of 64 o2
  int b = blockIdx.y;            // 32
  int n = threadIdx.x;           // 256
  const f16* b0 = sk + ((size_t)b * 512 + oc * 64) * 256 + n;
  const f16* b1 = b0 + (size_t)32 * 512 * 256;
  f16* wbase = Wh2T + ((size_t)b * 512 + oc * 64) * 256 + n;
  float s1 = 0.f, s2 = 0.f;
#pragma unroll 8
  for (int j = 0; j < 64; ++j) {
    float v = (float)b0[(size_t)j * 256] + (float)b1[(size_t)j * 256];
    int o2 = oc * 64 + j;
    s1 += v * ao[o2];
    s2 += v * ao[512 + o2];
    wbase[(size_t)j * 256] = (f16)v;
  }
  atomicAdd(&e12[b * 256 + n], s1);
  atomicAdd(&e22[b * 256 + n], s2);
}

#define PSTRIDE 264

// ---------------- fused attention layer 1 ----------------
// grid (h=8, b=32, nt=4)
__global__ __launch_bounds__(256, 4) void k_attn1(
    const f16* __restrict__ WhT, const float* __restrict__ e1g, const float* __restrict__ e2g,
    const int* __restrict__ adj, const float* __restrict__ npm, f16* __restrict__ h1) {
  int h = blockIdx.x, b = blockIdx.y, nt0 = blockIdx.z;
  int bh = b * 8 + h;
  int n0 = nt0 * 64;
  __shared__ f16 P[64 * PSTRIDE];
  int tid = threadIdx.x;
  int wave = tid >> 6, lane = tid & 63;

  float4 e2v = *(const float4*)&e2g[bh * 256 + lane * 4];
  float e2m = fmaxf(fmaxf(e2v.x, e2v.y), fmaxf(e2v.z, e2v.w));
#pragma unroll
  for (int m = 1; m < 64; m <<= 1) e2m = fmaxf(e2m, __shfl_xor(e2m, m));
#pragma unroll 4
  for (int i = 0; i < 16; ++i) {
    int row = i * 4 + wave;
    int gn = b * 256 + n0 + row;
    float er = e1g[bh * 256 + n0 + row];
    float sh = er + e2m;
    sh = sh > 0.f ? sh : 0.2f * sh;     // upper bound of row max
    int4 aj = *(const int4*)&adj[(size_t)gn * 256 + lane * 4];
    float p0, p1, p2, p3;
    {
      float v = er + e2v.x; v = v > 0.f ? v : 0.2f * v;
      p0 = aj.x ? __expf(v - sh) : 0.f;
      v = er + e2v.y; v = v > 0.f ? v : 0.2f * v;
      p1 = aj.y ? __expf(v - sh) : 0.f;
      v = er + e2v.z; v = v > 0.f ? v : 0.2f * v;
      p2 = aj.z ? __expf(v - sh) : 0.f;
      v = er + e2v.w; v = v > 0.f ? v : 0.2f * v;
      p3 = aj.w ? __expf(v - sh) : 0.f;
    }
    float sm = p0 + p1 + p2 + p3;
#pragma unroll
    for (int m = 1; m < 64; m <<= 1) sm += __shfl_xor(sm, m);
    float rs = 1.f / sm;
    f16x4 pw;
    pw[0] = (f16)(p0 * rs); pw[1] = (f16)(p1 * rs);
    pw[2] = (f16)(p2 * rs); pw[3] = (f16)(p3 * rs);
    *(f16x4*)&P[row * PSTRIDE + lane * 4] = pw;
  }
  __syncthreads();

  int lrow = lane & 15, quad = lane >> 4;
  f32x4 acc[4][4] = {};
  const f16* Ag = WhT + (size_t)bh * 65536;
#pragma unroll 2
  for (int k0 = 0; k0 < 256; k0 += 32) {
    f16x8 af[4], bf[4];
#pragma unroll
    for (int mt = 0; mt < 4; ++mt)
      af[mt] = *(const f16x8*)&Ag[(size_t)(wave * 64 + mt * 16 + lrow) * 256 + k0 + quad * 8];
#pragma unroll
    for (int nt = 0; nt < 4; ++nt)
      bf[nt] = *(const f16x8*)&P[(nt * 16 + lrow) * PSTRIDE + k0 + quad * 8];
#pragma unroll
    for (int mt = 0; mt < 4; ++mt)
#pragma unroll
      for (int nt = 0; nt < 4; ++nt)
        acc[mt][nt] = __builtin_amdgcn_mfma_f32_16x16x32_f16(af[mt], bf[nt], acc[mt][nt], 0, 0, 0);
  }
#pragma unroll
  for (int nt = 0; nt < 4; ++nt) {
    int nloc = nt * 16 + lrow;
    int gn = b * 256 + n0 + nloc;
    float pm = npm[gn];
#pragma unroll
    for (int mt = 0; mt < 4; ++mt) {
      int o0 = wave * 64 + mt * 16 + quad * 4;
      f16x4 st;
#pragma unroll
      for (int r = 0; r < 4; ++r) {
        float v = acc[mt][nt][r];
        v = v > 0.f ? v : (__expf(v) - 1.f);
        st[r] = (f16)(v * pm);
      }
      *(f16x4*)&h1[(size_t)gn * 2048 + h * 256 + o0] = st;
    }
  }
}

// ---------------- fused attention layer 2 ----------------
// grid (oh=2, b=32, nt=4)
__global__ __launch_bounds__(256, 4) void k_attn2(
    const f16* __restrict__ Wh2T, const float* __restrict__ e1g, const float* __restrict__ e2g,
    const int* __restrict__ adj, const float* __restrict__ npm, float* __restrict__ out) {
  int oh = blockIdx.x, b = blockIdx.y, nt0 = blockIdx.z;
  int n0 = nt0 * 64;
  __shared__ f16 P[64 * PSTRIDE];
  int tid = threadIdx.x;
  int wave = tid >> 6, lane = tid & 63;

  float4 e2v = *(const float4*)&e2g[b * 256 + lane * 4];
  float e2m = fmaxf(fmaxf(e2v.x, e2v.y), fmaxf(e2v.z, e2v.w));
#pragma unroll
  for (int m = 1; m < 64; m <<= 1) e2m = fmaxf(e2m, __shfl_xor(e2m, m));
#pragma unroll 4
  for (int i = 0; i < 16; ++i) {
    int row = i * 4 + wave;
    int gn = b * 256 + n0 + row;
    float er = e1g[b * 256 + n0 + row];
    float sh = er + e2m;
    sh = sh > 0.f ? sh : 0.2f * sh;
    int4 aj = *(const int4*)&adj[(size_t)gn * 256 + lane * 4];
    float p0, p1, p2, p3;
    {
      float v = er + e2v.x; v = v > 0.f ? v : 0.2f * v;
      p0 = aj.x ? __expf(v - sh) : 0.f;
      v = er + e2v.y; v = v > 0.f ? v : 0.2f * v;
      p1 = aj.y ? __expf(v - sh) : 0.f;
      v = er + e2v.z; v = v > 0.f ? v : 0.2f * v;
      p2 = aj.z ? __expf(v - sh) : 0.f;
      v = er + e2v.w; v = v > 0.f ? v : 0.2f * v;
      p3 = aj.w ? __expf(v - sh) : 0.f;
    }
    float sm = p0 + p1 + p2 + p3;
#pragma unroll
    for (int m = 1; m < 64; m <<= 1) sm += __shfl_xor(sm, m);
    float rs = 1.f / sm;
    f16x4 pw;
    pw[0] = (f16)(p0 * rs); pw[1] = (f16)(p1 * rs);
    pw[2] = (f16)(p2 * rs); pw[3] = (f16)(p3 * rs);
    *(f16x4*)&P[row * PSTRIDE + lane * 4] = pw;
  }
  __syncthreads();

  int lrow = lane & 15, quad = lane >> 4;
  f32x4 acc[4][4] = {};
  const f16* Ag = Wh2T + (size_t)b * 512 * 256 + (size_t)oh * 65536;
#pragma unroll 2
  for (int k0 = 0; k0 < 256; k0 += 32) {
    f16x8 af[4], bf[4];
#pragma unroll
    for (int mt = 0; mt < 4; ++mt)
      af[mt] = *(const f16x8*)&Ag[(size_t)(wave * 64 + mt * 16 + lrow) * 256 + k0 + quad * 8];
#pragma unroll
    for (int nt = 0; nt < 4; ++nt)
      bf[nt] = *(const f16x8*)&P[(nt * 16 + lrow) * PSTRIDE + k0 + quad * 8];
#pragma unroll
    for (int mt = 0; mt < 4; ++mt)
#pragma unroll
      for (int nt = 0; nt < 4; ++nt)
        acc[mt][nt] = __builtin_amdgcn_mfma_f32_16x16x32_f16(af[mt], bf[nt], acc[mt][nt], 0, 0, 0);
  }
#pragma unroll
  for (int nt = 0; nt < 4; ++nt) {
    int nloc = nt * 16 + lrow;
    int gn = b * 256 + n0 + nloc;
    float pm = npm[gn];
#pragma unroll
    for (int mt = 0; mt < 4; ++mt) {
      int o0 = oh * 256 + wave * 64 + mt * 16 + quad * 4;
      float4 st;
      float v0 = acc[mt][nt][0] * pm;
      float v1 = acc[mt][nt][1] * pm;
      float v2 = acc[mt][nt][2] * pm;
      float v3 = acc[mt][nt][3] * pm;
      st.x = v0 > 0.f ? v0 : (__expf(v0) - 1.f);
      st.y = v1 > 0.f ? v1 : (__expf(v1) - 1.f);
      st.z = v2 > 0.f ? v2 : (__expf(v2) - 1.f);
      st.w = v3 > 0.f ? v3 : (__expf(v3) - 1.f);
      *(float4*)&out[(size_t)gn * 512 + o0] = st;
    }
  }
}

extern "C" void kernel_launch(void* const* d_in, const int* in_sizes, int n_in,
                              void* d_out, int out_size, void* d_ws, size_t ws_size,
                              hipStream_t stream) {
  (void)in_sizes; (void)n_in; (void)out_size; (void)ws_size;
  const int*   fea   = (const int*)d_in[0];
  const int*   adj   = (const int*)d_in[1];
  const float* npm   = (const float*)d_in[2];
  const float* embed = (const float*)d_in[3];
  const float* Whd   = (const float*)d_in[4];
  const float* ah    = (const float*)d_in[5];
  const float* Wo    = (const float*)d_in[6];
  const float* ao    = (const float*)d_in[7];
  float* out = (float*)d_out;

  char* ws = (char*)d_ws;
  f16* x16  = (f16*)ws;  ws += (size_t)8192 * 320 * 2;
  f16* WcT  = (f16*)ws;  ws += (size_t)2048 * 320 * 2;
  f16* WoT  = (f16*)ws;  ws += (size_t)512 * 2048 * 2;
  f16* WhT  = (f16*)ws;  ws += (size_t)32 * 8 * 256 * 256 * 2;   // [b][h*256+o][n]
  f16* h1   = (f16*)ws;  ws += (size_t)8192 * 2048 * 2;          // [bn][h*256+o]
  f16* Wh2T = (f16*)ws;  ws += (size_t)32 * 512 * 256 * 2;       // [b][o2][n]
  f16* Wh2sk = (f16*)ws; ws += (size_t)2 * 32 * 512 * 256 * 2;   // split-K halves (f16)
  float* e1  = (float*)ws; ws += (size_t)65536 * 4;
  float* e2  = (float*)ws; ws += (size_t)65536 * 4;
  float* e12 = (float*)ws; ws += (size_t)8192 * 4;
  float* e22 = (float*)ws; ws += (size_t)8192 * 4;

  // zero only the e-accumulators (contiguous)
  hipMemsetAsync(e1, 0, ((size_t)65536 * 2 + 8192 * 2) * 4, stream);

  k_prep_x<<<8192, 320, 0, stream>>>(fea, embed, x16);
  k_prep_wc<<<dim3(10, 8, 8), 256, 0, stream>>>(Whd, WcT);
  k_prep_wo<<<dim3(64, 16), 256, 0, stream>>>(Wo, WoT);

  k_gemm1<320, 2048><<<dim3(64, 16), 256, 0, stream>>>(x16, WcT, WhT, ah, e1, e2);
  k_attn1<<<dim3(8, 32, 4), 256, 0, stream>>>(WhT, e1, e2, adj, npm, h1);

  k_gemm_sk<<<dim3(64, 8, 2), 256, 0, stream>>>(h1, WoT, Wh2sk);
  k_comb<<<dim3(8, 32), 256, 0, stream>>>(Wh2sk, ao, Wh2T, e12, e22);
  k_attn2<<<dim3(2, 32, 4), 256, 0, stream>>>(Wh2T, e12, e22, adj, npm, out);
}

// Round 7
// 200.130 us; speedup vs baseline: 1.9856x; 1.0368x over previous
//
#include <hip/hip_runtime.h>
#include <math.h>

// GAT forward: B=32 N=256 F=300(pad 320) O=256 H=8 OUT=512

typedef _Float16 f16;
typedef __attribute__((ext_vector_type(8))) _Float16 f16x8;
typedef __attribute__((ext_vector_type(4))) _Float16 f16x4;
typedef __attribute__((ext_vector_type(4))) float f32x4;

__device__ __forceinline__ void async16(const void* g, void* lds) {
  __builtin_amdgcn_global_load_lds(
      (const __attribute__((address_space(1))) void*)g,
      (__attribute__((address_space(3))) void*)lds, 16, 0, 0);
}

// ---------------- fused prep: x16 + WcT + WoT + e-zero ----------------
// blocks [0,1280): x16 chunks; [1280,1920): WcT transpose + e-zero; [1920,2944): WoT.
__global__ __launch_bounds__(256) void k_prep(const int* __restrict__ fea,
                                              const float* __restrict__ embed,
                                              const float* __restrict__ Whd,
                                              const float* __restrict__ Wo,
                                              f16* __restrict__ x16,
                                              f16* __restrict__ WcT,
                                              f16* __restrict__ WoT,
                                              float* __restrict__ e_all) {
  int bid = blockIdx.x, tid = threadIdx.x;
  if (bid < 1280) {
    // x16: 8192 rows x 40 chunks of 8 f16 (16B store per thread)
    int idx = bid * 256 + tid;          // < 327680
    int row = idx / 40, c = idx % 40;
    int tok = fea[row];
    const float* eb = embed + (size_t)tok * 300;
    f16x8 v;
#pragma unroll
    for (int j = 0; j < 8; ++j) {
      int t = c * 8 + j;
      v[j] = (f16)((t < 300) ? eb[t] : 0.f);
    }
    *(f16x8*)&x16[(size_t)row * 320 + c * 8] = v;
  } else if (bid < 1920) {
    int r = bid - 1280;                 // < 640
    // zero e-accumulators (147456 floats, contiguous)
    int zi = r * 256 + tid;
    if (zi < 147456) e_all[zi] = 0.f;
    // WcT: W[h][t<300][o<256] -> WcT[(h*256+o)*320 + t]
    __shared__ float tile[32][33];
    int bx = r % 10, q0 = r / 10;
    int by = q0 % 8, h = q0 / 8;
    int c = tid & 31, q = tid >> 5;
#pragma unroll
    for (int i = 0; i < 4; ++i) {
      int tt = q + i * 8;
      int t = bx * 32 + tt;
      float v = (t < 300) ? Whd[((size_t)h * 300 + t) * 256 + by * 32 + c] : 0.f;
      tile[tt][c] = v;
    }
    __syncthreads();
#pragma unroll
    for (int i = 0; i < 4; ++i) {
      int oo = q + i * 8;
      int gc = h * 256 + by * 32 + oo;
      WcT[(size_t)gc * 320 + bx * 32 + c] = (f16)tile[c][oo];
    }
  } else {
    int r = bid - 1920;                 // < 1024
    // WoT: W[k<2048][o2<512] -> WoT[o2*2048 + k]
    __shared__ float tile[32][33];
    int bx = r % 64, by = r / 64;
    int c = tid & 31, q = tid >> 5;
#pragma unroll
    for (int i = 0; i < 4; ++i) {
      int kk = q + i * 8;
      tile[kk][c] = Wo[((size_t)bx * 32 + kk) * 512 + by * 32 + c];
    }
    __syncthreads();
#pragma unroll
    for (int i = 0; i < 4; ++i) {
      int oo = q + i * 8;
      WoT[((size_t)by * 32 + oo) * 2048 + bx * 32 + c] = (f16)tile[c][oo];
    }
  }
}

// ---------------- GEMM 1 + fused e-dots, BK=64 ----------------
// outT[b][col][n] = (A @ BT^T)^T, tile 128x128.
// 8-chunk XOR swizzle: LDS[row][p] = G[row][p ^ (row&7)] (16B chunks).
template <int KDIM, int NCOLS>
__global__ __launch_bounds__(256, 4) void k_gemm1(const f16* __restrict__ A,
                                                  const f16* __restrict__ BT,
                                                  f16* __restrict__ outT,
                                                  const float* __restrict__ avec,
                                                  float* __restrict__ e1,
                                                  float* __restrict__ e2) {
  __shared__ f16 As[128 * 64];
  __shared__ f16 Bs[128 * 64];
  const int by = blockIdx.x, bx = blockIdx.y;   // A-row-tile fastest (XCD locality)
  const int tid = threadIdx.x;
  const int wave = tid >> 6, lane = tid & 63;
  const int wm = wave >> 1, wn = wave & 1;
  const int lrow = lane & 15, quad = lane >> 4;
  const int srow = lane >> 3;                          // 8 rows per staging inst
  const int scol = ((lane & 7) ^ (lane >> 3)) * 8;     // swizzled source chunk
  const int l7 = lrow & 7;

  f32x4 acc[4][4] = {};
  const f16* Ag = A + (size_t)by * 128 * KDIM;
  const f16* Bg = BT + (size_t)bx * 128 * KDIM;

  for (int k0 = 0; k0 < KDIM; k0 += 64) {
    __syncthreads();
#pragma unroll
    for (int j = 0; j < 4; ++j) {
      const int r0 = wave * 32 + j * 8;
      async16(Ag + (size_t)(r0 + srow) * KDIM + k0 + scol, &As[r0 * 64]);
      async16(Bg + (size_t)(r0 + srow) * KDIM + k0 + scol, &Bs[r0 * 64]);
    }
    __syncthreads();
#pragma unroll
    for (int s = 0; s < 2; ++s) {
      const int sq = ((s * 4 + quad) ^ l7) * 8;
      f16x8 af[4], bf[4];
#pragma unroll
      for (int t = 0; t < 4; ++t) {
        af[t] = *(const f16x8*)&As[(wm * 64 + t * 16 + lrow) * 64 + sq];
        bf[t] = *(const f16x8*)&Bs[(wn * 64 + t * 16 + lrow) * 64 + sq];
      }
#pragma unroll
      for (int mt = 0; mt < 4; ++mt)
#pragma unroll
        for (int nt = 0; nt < 4; ++nt)
          acc[mt][nt] = __builtin_amdgcn_mfma_f32_16x16x32_f16(af[mt], bf[nt], acc[mt][nt], 0, 0, 0);
    }
  }

  const int b = (by * 128) >> 8;
  const int nbase0 = (by * 128) & 255;
#pragma unroll
  for (int mt = 0; mt < 4; ++mt) {
    const int nb = nbase0 + wm * 64 + mt * 16 + quad * 4;
#pragma unroll
    for (int nt = 0; nt < 4; ++nt) {
      const int gc = bx * 128 + wn * 64 + nt * 16 + lrow;
      f16x4 v;
#pragma unroll
      for (int r = 0; r < 4; ++r) v[r] = (f16)acc[mt][nt][r];
      *(f16x4*)&outT[((size_t)b * NCOLS + gc) * 256 + nb] = v;
    }
  }

  // fused e-dot vs a_heads (block spans one head: 128 cols within h)
  float a1v[4], a2v[4];
#pragma unroll
  for (int nt = 0; nt < 4; ++nt) {
    const int gc = bx * 128 + wn * 64 + nt * 16 + lrow;
    int hh = gc >> 8, oo = gc & 255;
    a1v[nt] = avec[hh * 512 + oo];
    a2v[nt] = avec[hh * 512 + 256 + oo];
  }
  const int hblk = (bx * 128) >> 8;
  const int ebase = (b * 8 + hblk) * 256;
#pragma unroll
  for (int mt = 0; mt < 4; ++mt) {
    float s1[4] = {0.f, 0.f, 0.f, 0.f}, s2[4] = {0.f, 0.f, 0.f, 0.f};
#pragma unroll
    for (int nt = 0; nt < 4; ++nt)
#pragma unroll
      for (int r = 0; r < 4; ++r) {
        s1[r] += acc[mt][nt][r] * a1v[nt];
        s2[r] += acc[mt][nt][r] * a2v[nt];
      }
#pragma unroll
    for (int r = 0; r < 4; ++r)
#pragma unroll
      for (int m = 1; m < 16; m <<= 1) {
        s1[r] += __shfl_xor(s1[r], m);
        s2[r] += __shfl_xor(s2[r], m);
      }
    if (lrow == 0) {
      const int nb = nbase0 + wm * 64 + mt * 16 + quad * 4;
#pragma unroll
      for (int r = 0; r < 4; ++r) {
        atomicAdd(&e1[ebase + nb + r], s1[r]);
        atomicAdd(&e2[ebase + nb + r], s2[r]);
      }
    }
  }
}

// ---------------- GEMM 2: split-K x2 into disjoint f16 buffers, BK=64 ----------------
// M=8192, N=512, K=2048; tile 128x64, K-chunk 1024; grid (64, 8, 2) = 1024 blocks = 4/CU.
__global__ __launch_bounds__(256, 4) void k_gemm_sk(const f16* __restrict__ A,
                                                    const f16* __restrict__ BT,
                                                    f16* __restrict__ outSK) {
  __shared__ f16 As[128 * 64];
  __shared__ f16 Bs[64 * 64];
  const int by = blockIdx.x, bx = blockIdx.y, kz = blockIdx.z;
  const int tid = threadIdx.x;
  const int wave = tid >> 6, lane = tid & 63;
  const int wm = wave >> 1, wn = wave & 1;
  const int lrow = lane & 15, quad = lane >> 4;
  const int srow = lane >> 3;
  const int scol = ((lane & 7) ^ (lane >> 3)) * 8;
  const int l7 = lrow & 7;

  f32x4 acc[4][2] = {};
  const f16* Ag = A + (size_t)by * 128 * 2048;
  const f16* Bg = BT + (size_t)bx * 64 * 2048;
  const int kbeg = kz * 1024;

  for (int k0 = kbeg; k0 < kbeg + 1024; k0 += 64) {
    __syncthreads();
#pragma unroll
    for (int j = 0; j < 4; ++j) {
      const int r0 = wave * 32 + j * 8;
      async16(Ag + (size_t)(r0 + srow) * 2048 + k0 + scol, &As[r0 * 64]);
    }
#pragma unroll
    for (int j = 0; j < 2; ++j) {
      const int r0 = wave * 16 + j * 8;
      async16(Bg + (size_t)(r0 + srow) * 2048 + k0 + scol, &Bs[r0 * 64]);
    }
    __syncthreads();
#pragma unroll
    for (int s = 0; s < 2; ++s) {
      const int sq = ((s * 4 + quad) ^ l7) * 8;
      f16x8 af[4], bf[2];
#pragma unroll
      for (int t = 0; t < 4; ++t)
        af[t] = *(const f16x8*)&As[(wm * 64 + t * 16 + lrow) * 64 + sq];
#pragma unroll
      for (int t = 0; t < 2; ++t)
        bf[t] = *(const f16x8*)&Bs[(wn * 32 + t * 16 + lrow) * 64 + sq];
#pragma unroll
      for (int mt = 0; mt < 4; ++mt)
#pragma unroll
        for (int nt = 0; nt < 2; ++nt)
          acc[mt][nt] = __builtin_amdgcn_mfma_f32_16x16x32_f16(af[mt], bf[nt], acc[mt][nt], 0, 0, 0);
    }
  }

  const int b = (by * 128) >> 8;
  const int nbase0 = (by * 128) & 255;
  f16* dst = outSK + (size_t)kz * 32 * 512 * 256;
#pragma unroll
  for (int mt = 0; mt < 4; ++mt) {
    const int nb = nbase0 + wm * 64 + mt * 16 + quad * 4;
#pragma unroll
    for (int nt = 0; nt < 2; ++nt) {
      const int gc = bx * 64 + wn * 32 + nt * 16 + lrow;
      f16x4 v;
#pragma unroll
      for (int r = 0; r < 4; ++r) v[r] = (f16)acc[mt][nt][r];
      *(f16x4*)&dst[((size_t)b * 512 + gc) * 256 + nb] = v;
    }
  }
}

// ---------------- combine: sum 2 split-K halves -> f16 Wh2T, fused e12/e22 dots ----------------
__global__ void k_comb(const f16* __restrict__ sk, const float* __restrict__ ao,
                       f16* __restrict__ Wh2T, float* __restrict__ e12,
                       float* __restrict__ e22) {
  int oc = blockIdx.x;           // 16 chunks of 32 o2
  int b = blockIdx.y;            // 32
  int n = threadIdx.x;           // 256
  const f16* b0 = sk + ((size_t)b * 512 + oc * 32) * 256 + n;
  const f16* b1 = b0 + (size_t)32 * 512 * 256;
  f16* wbase = Wh2T + ((size_t)b * 512 + oc * 32) * 256 + n;
  float s1 = 0.f, s2 = 0.f;
#pragma unroll 8
  for (int j = 0; j < 32; ++j) {
    float v = (float)b0[(size_t)j * 256] + (float)b1[(size_t)j * 256];
    int o2 = oc * 32 + j;
    s1 += v * ao[o2];
    s2 += v * ao[512 + o2];
    wbase[(size_t)j * 256] = (f16)v;
  }
  atomicAdd(&e12[b * 256 + n], s1);
  atomicAdd(&e22[b * 256 + n], s2);
}

#define PSTRIDE 264

// ---------------- fused attention layer 1 ----------------
// grid (h=8, b=32, nt=4)
__global__ __launch_bounds__(256, 4) void k_attn1(
    const f16* __restrict__ WhT, const float* __restrict__ e1g, const float* __restrict__ e2g,
    const int* __restrict__ adj, const float* __restrict__ npm, f16* __restrict__ h1) {
  int h = blockIdx.x, b = blockIdx.y, nt0 = blockIdx.z;
  int bh = b * 8 + h;
  int n0 = nt0 * 64;
  __shared__ f16 P[64 * PSTRIDE];
  int tid = threadIdx.x;
  int wave = tid >> 6, lane = tid & 63;

  float4 e2v = *(const float4*)&e2g[bh * 256 + lane * 4];
  float e2m = fmaxf(fmaxf(e2v.x, e2v.y), fmaxf(e2v.z, e2v.w));
#pragma unroll
  for (int m = 1; m < 64; m <<= 1) e2m = fmaxf(e2m, __shfl_xor(e2m, m));
#pragma unroll 4
  for (int i = 0; i < 16; ++i) {
    int row = i * 4 + wave;
    int gn = b * 256 + n0 + row;
    float er = e1g[bh * 256 + n0 + row];
    float sh = er + e2m;
    sh = sh > 0.f ? sh : 0.2f * sh;     // upper bound of row max
    int4 aj = *(const int4*)&adj[(size_t)gn * 256 + lane * 4];
    float p0, p1, p2, p3;
    {
      float v = er + e2v.x; v = v > 0.f ? v : 0.2f * v;
      p0 = aj.x ? __expf(v - sh) : 0.f;
      v = er + e2v.y; v = v > 0.f ? v : 0.2f * v;
      p1 = aj.y ? __expf(v - sh) : 0.f;
      v = er + e2v.z; v = v > 0.f ? v : 0.2f * v;
      p2 = aj.z ? __expf(v - sh) : 0.f;
      v = er + e2v.w; v = v > 0.f ? v : 0.2f * v;
      p3 = aj.w ? __expf(v - sh) : 0.f;
    }
    float sm = p0 + p1 + p2 + p3;
#pragma unroll
    for (int m = 1; m < 64; m <<= 1) sm += __shfl_xor(sm, m);
    float rs = 1.f / sm;
    f16x4 pw;
    pw[0] = (f16)(p0 * rs); pw[1] = (f16)(p1 * rs);
    pw[2] = (f16)(p2 * rs); pw[3] = (f16)(p3 * rs);
    *(f16x4*)&P[row * PSTRIDE + lane * 4] = pw;
  }
  __syncthreads();

  int lrow = lane & 15, quad = lane >> 4;
  f32x4 acc[4][4] = {};
  const f16* Ag = WhT + (size_t)bh * 65536;
#pragma unroll 2
  for (int k0 = 0; k0 < 256; k0 += 32) {
    f16x8 af[4], bf[4];
#pragma unroll
    for (int mt = 0; mt < 4; ++mt)
      af[mt] = *(const f16x8*)&Ag[(size_t)(wave * 64 + mt * 16 + lrow) * 256 + k0 + quad * 8];
#pragma unroll
    for (int nt = 0; nt < 4; ++nt)
      bf[nt] = *(const f16x8*)&P[(nt * 16 + lrow) * PSTRIDE + k0 + quad * 8];
#pragma unroll
    for (int mt = 0; mt < 4; ++mt)
#pragma unroll
      for (int nt = 0; nt < 4; ++nt)
        acc[mt][nt] = __builtin_amdgcn_mfma_f32_16x16x32_f16(af[mt], bf[nt], acc[mt][nt], 0, 0, 0);
  }
#pragma unroll
  for (int nt = 0; nt < 4; ++nt) {
    int nloc = nt * 16 + lrow;
    int gn = b * 256 + n0 + nloc;
    float pm = npm[gn];
#pragma unroll
    for (int mt = 0; mt < 4; ++mt) {
      int o0 = wave * 64 + mt * 16 + quad * 4;
      f16x4 st;
#pragma unroll
      for (int r = 0; r < 4; ++r) {
        float v = acc[mt][nt][r];
        v = v > 0.f ? v : (__expf(v) - 1.f);
        st[r] = (f16)(v * pm);
      }
      *(f16x4*)&h1[(size_t)gn * 2048 + h * 256 + o0] = st;
    }
  }
}

// ---------------- fused attention layer 2 ----------------
// grid (oh=2, b=32, nt=4)
__global__ __launch_bounds__(256, 4) void k_attn2(
    const f16* __restrict__ Wh2T, const float* __restrict__ e1g, const float* __restrict__ e2g,
    const int* __restrict__ adj, const float* __restrict__ npm, float* __restrict__ out) {
  int oh = blockIdx.x, b = blockIdx.y, nt0 = blockIdx.z;
  int n0 = nt0 * 64;
  __shared__ f16 P[64 * PSTRIDE];
  int tid = threadIdx.x;
  int wave = tid >> 6, lane = tid & 63;

  float4 e2v = *(const float4*)&e2g[b * 256 + lane * 4];
  float e2m = fmaxf(fmaxf(e2v.x, e2v.y), fmaxf(e2v.z, e2v.w));
#pragma unroll
  for (int m = 1; m < 64; m <<= 1) e2m = fmaxf(e2m, __shfl_xor(e2m, m));
#pragma unroll 4
  for (int i = 0; i < 16; ++i) {
    int row = i * 4 + wave;
    int gn = b * 256 + n0 + row;
    float er = e1g[b * 256 + n0 + row];
    float sh = er + e2m;
    sh = sh > 0.f ? sh : 0.2f * sh;
    int4 aj = *(const int4*)&adj[(size_t)gn * 256 + lane * 4];
    float p0, p1, p2, p3;
    {
      float v = er + e2v.x; v = v > 0.f ? v : 0.2f * v;
      p0 = aj.x ? __expf(v - sh) : 0.f;
      v = er + e2v.y; v = v > 0.f ? v : 0.2f * v;
      p1 = aj.y ? __expf(v - sh) : 0.f;
      v = er + e2v.z; v = v > 0.f ? v : 0.2f * v;
      p2 = aj.z ? __expf(v - sh) : 0.f;
      v = er + e2v.w; v = v > 0.f ? v : 0.2f * v;
      p3 = aj.w ? __expf(v - sh) : 0.f;
    }
    float sm = p0 + p1 + p2 + p3;
#pragma unroll
    for (int m = 1; m < 64; m <<= 1) sm += __shfl_xor(sm, m);
    float rs = 1.f / sm;
    f16x4 pw;
    pw[0] = (f16)(p0 * rs); pw[1] = (f16)(p1 * rs);
    pw[2] = (f16)(p2 * rs); pw[3] = (f16)(p3 * rs);
    *(f16x4*)&P[row * PSTRIDE + lane * 4] = pw;
  }
  __syncthreads();

  int lrow = lane & 15, quad = lane >> 4;
  f32x4 acc[4][4] = {};
  const f16* Ag = Wh2T + (size_t)b * 512 * 256 + (size_t)oh * 65536;
#pragma unroll 2
  for (int k0 = 0; k0 < 256; k0 += 32) {
    f16x8 af[4], bf[4];
#pragma unroll
    for (int mt = 0; mt < 4; ++mt)
      af[mt] = *(const f16x8*)&Ag[(size_t)(wave * 64 + mt * 16 + lrow) * 256 + k0 + quad * 8];
#pragma unroll
    for (int nt = 0; nt < 4; ++nt)
      bf[nt] = *(const f16x8*)&P[(nt * 16 + lrow) * PSTRIDE + k0 + quad * 8];
#pragma unroll
    for (int mt = 0; mt < 4; ++mt)
#pragma unroll
      for (int nt = 0; nt < 4; ++nt)
        acc[mt][nt] = __builtin_amdgcn_mfma_f32_16x16x32_f16(af[mt], bf[nt], acc[mt][nt], 0, 0, 0);
  }
#pragma unroll
  for (int nt = 0; nt < 4; ++nt) {
    int nloc = nt * 16 + lrow;
    int gn = b * 256 + n0 + nloc;
    float pm = npm[gn];
#pragma unroll
    for (int mt = 0; mt < 4; ++mt) {
      int o0 = oh * 256 + wave * 64 + mt * 16 + quad * 4;
      float4 st;
      float v0 = acc[mt][nt][0] * pm;
      float v1 = acc[mt][nt][1] * pm;
      float v2 = acc[mt][nt][2] * pm;
      float v3 = acc[mt][nt][3] * pm;
      st.x = v0 > 0.f ? v0 : (__expf(v0) - 1.f);
      st.y = v1 > 0.f ? v1 : (__expf(v1) - 1.f);
      st.z = v2 > 0.f ? v2 : (__expf(v2) - 1.f);
      st.w = v3 > 0.f ? v3 : (__expf(v3) - 1.f);
      *(float4*)&out[(size_t)gn * 512 + o0] = st;
    }
  }
}

extern "C" void kernel_launch(void* const* d_in, const int* in_sizes, int n_in,
                              void* d_out, int out_size, void* d_ws, size_t ws_size,
                              hipStream_t stream) {
  (void)in_sizes; (void)n_in; (void)out_size; (void)ws_size;
  const int*   fea   = (const int*)d_in[0];
  const int*   adj   = (const int*)d_in[1];
  const float* npm   = (const float*)d_in[2];
  const float* embed = (const float*)d_in[3];
  const float* Whd   = (const float*)d_in[4];
  const float* ah    = (const float*)d_in[5];
  const float* Wo    = (const float*)d_in[6];
  const float* ao    = (const float*)d_in[7];
  float* out = (float*)d_out;

  char* ws = (char*)d_ws;
  f16* x16  = (f16*)ws;  ws += (size_t)8192 * 320 * 2;
  f16* WcT  = (f16*)ws;  ws += (size_t)2048 * 320 * 2;
  f16* WoT  = (f16*)ws;  ws += (size_t)512 * 2048 * 2;
  f16* WhT  = (f16*)ws;  ws += (size_t)32 * 8 * 256 * 256 * 2;   // [b][h*256+o][n]
  f16* h1   = (f16*)ws;  ws += (size_t)8192 * 2048 * 2;          // [bn][h*256+o]
  f16* Wh2T = (f16*)ws;  ws += (size_t)32 * 512 * 256 * 2;       // [b][o2][n]
  f16* Wh2sk = (f16*)ws; ws += (size_t)2 * 32 * 512 * 256 * 2;   // split-K halves (f16)
  float* e1  = (float*)ws; ws += (size_t)65536 * 4;
  float* e2  = (float*)ws; ws += (size_t)65536 * 4;
  float* e12 = (float*)ws; ws += (size_t)8192 * 4;
  float* e22 = (float*)ws; ws += (size_t)8192 * 4;

  // k_prep zeroes e1..e22 (contiguous 147456 floats) in-kernel
  k_prep<<<2944, 256, 0, stream>>>(fea, embed, Whd, Wo, x16, WcT, WoT, e1);

  k_gemm1<320, 2048><<<dim3(64, 16), 256, 0, stream>>>(x16, WcT, WhT, ah, e1, e2);
  k_attn1<<<dim3(8, 32, 4), 256, 0, stream>>>(WhT, e1, e2, adj, npm, h1);

  k_gemm_sk<<<dim3(64, 8, 2), 256, 0, stream>>>(h1, WoT, Wh2sk);
  k_comb<<<dim3(16, 32), 256, 0, stream>>>(Wh2sk, ao, Wh2T, e12, e22);
  k_attn2<<<dim3(2, 32, 4), 256, 0, stream>>>(Wh2T, e12, e22, adj, npm, out);
}